// Round 3
// baseline (328.192 us; speedup 1.0000x reference)
//
#include <hip/hip_runtime.h>

typedef __bf16 bf16;
using short8 = __attribute__((ext_vector_type(8))) short;
using f32x4  = __attribute__((ext_vector_type(4))) float;

#define N_TOK 4128
#define N_PAD 4160
#define QD    320
#define DH    40
#define W_VIS 4096

__device__ __forceinline__ short cvt1(float x) {
  __bf16 h = (__bf16)x;
  return __builtin_bit_cast(short, h);
}

// dtype-aware scalar load (element index)
__device__ __forceinline__ float loadS(const void* b, long i, bool isbf) {
  return isbf ? (float)((const bf16*)b)[i] : ((const float*)b)[i];
}

// dtype-aware 8-element MFMA fragment load (element offset, 16B/32B aligned)
__device__ __forceinline__ short8 load_frag8(const void* base, long off, bool isbf) {
  if (isbf) return *(const short8*)((const bf16*)base + off);
  const float* f = (const float*)base + off;
  float4 a = *(const float4*)f;
  float4 c = *(const float4*)(f + 4);
  short8 r;
  r[0] = cvt1(a.x); r[1] = cvt1(a.y); r[2] = cvt1(a.z); r[3] = cvt1(a.w);
  r[4] = cvt1(c.x); r[5] = cvt1(c.y); r[6] = cvt1(c.z); r[7] = cvt1(c.w);
  return r;
}

// ---------- dtype sniffer: att_masks is exactly {0,1}. fp32 -> even halfwords
// are always 0x0000; bf16 -> ~15% of even halfwords are 0x3F80. ----------
__global__ __launch_bounds__(256) void sniff_kernel(const unsigned short* att_h,
                                                    int* flag) {
  __shared__ int s;
  if (threadIdx.x == 0) s = 0;
  __syncthreads();
  int any = 0;
  for (int i = threadIdx.x; i < 4096; i += 256) any |= (att_h[2 * i] != 0);
  if (any) atomicOr(&s, 1);
  __syncthreads();
  if (threadIdx.x == 0) flag[0] = s;   // 1 = bf16 inputs, 0 = fp32 inputs
}

// ---------- prep: transpose 4 weights (320x320) to [n][k] (bf16), build mask words ----------
__global__ __launch_bounds__(256) void prep_kernel(
    const void* __restrict__ att,
    const void* __restrict__ Wq, const void* __restrict__ Wk,
    const void* __restrict__ Wv, const void* __restrict__ Wo,
    bf16* __restrict__ Wqt, bf16* __restrict__ Wkt,
    bf16* __restrict__ Wvt, bf16* __restrict__ Wot,
    unsigned int* __restrict__ mask32, const int* __restrict__ flag) {
  bool isbf = flag[0] != 0;
  int id = blockIdx.x * 256 + threadIdx.x;
  if (id < 4 * 102400) {
    int wsel = id / 102400;
    int r = id % 102400;
    int k = r / 320, n = r % 320;
    const void* src = wsel == 0 ? Wq : wsel == 1 ? Wk : wsel == 2 ? Wv : Wo;
    bf16* dst       = wsel == 0 ? Wqt : wsel == 1 ? Wkt : wsel == 2 ? Wvt : Wot;
    dst[n * 320 + k] = (bf16)loadS(src, k * 320 + n, isbf);
  } else {
    int t = id - 4 * 102400;
    if (t < N_PAD) {
      unsigned int w = 0u;
      if (t < W_VIS) {
        unsigned int b = 0u;
#pragma unroll
        for (int o = 0; o < 8; ++o)
          if (loadS(att, o * W_VIS + t, isbf) != 0.0f) b |= (1u << o);
        w = b;
      } else if (t < N_TOK) {
        int g = t - W_VIS;
        int rep = g >> 3, o = g & 7;
        w = 0x100u | ((rep == 1 || rep == 2) ? 0x8000u : (1u << o));
      }
      mask32[t] = w;
    }
  }
}

// ---------- fused QKV GEMM: C = A[4128x320] * Bt[320x320]^T, NT ----------
__global__ __launch_bounds__(256) void gemm_qkv(
    const void* __restrict__ A,
    const bf16* __restrict__ Bq, const bf16* __restrict__ Bk, const bf16* __restrict__ Bv,
    bf16* __restrict__ q, bf16* __restrict__ k, bf16* __restrict__ vt,
    const int* __restrict__ flag) {
  bool isbf = flag[0] != 0;
  int m0 = blockIdx.x * 64;
  int ng = blockIdx.y * 64;            // 0..896 across q|k|v
  int wsel = ng / 320;                 // 0=q 1=k 2=v
  int n_in = ng % 320;
  const bf16* Bt = wsel == 0 ? Bq : wsel == 1 ? Bk : Bv;
  int wv = threadIdx.x >> 6, lane = threadIdx.x & 63;
  int quad = lane >> 4, li = lane & 15;
  int wm = wv >> 1, wn = wv & 1;       // 2x2 waves, 32x32 each
  f32x4 acc[2][2];
#pragma unroll
  for (int a = 0; a < 2; a++)
#pragma unroll
    for (int b = 0; b < 2; b++) acc[a][b] = (f32x4){0.f, 0.f, 0.f, 0.f};
#pragma unroll
  for (int ks = 0; ks < 10; ++ks) {
    short8 af[2], bfrag[2];
#pragma unroll
    for (int mt = 0; mt < 2; ++mt) {
      int r = m0 + wm * 32 + mt * 16 + li;
      r = r < N_TOK ? r : N_TOK - 1;
      af[mt] = load_frag8(A, (long)r * QD + ks * 32 + quad * 8, isbf);
    }
#pragma unroll
    for (int nt = 0; nt < 2; ++nt) {
      int r = n_in + wn * 32 + nt * 16 + li;
      bfrag[nt] = *(const short8*)(Bt + r * QD + ks * 32 + quad * 8);
    }
#pragma unroll
    for (int mt = 0; mt < 2; ++mt)
#pragma unroll
      for (int nt = 0; nt < 2; ++nt)
        acc[mt][nt] = __builtin_amdgcn_mfma_f32_16x16x32_bf16(af[mt], bfrag[nt], acc[mt][nt], 0, 0, 0);
  }
#pragma unroll
  for (int mt = 0; mt < 2; ++mt)
#pragma unroll
    for (int nt = 0; nt < 2; ++nt)
#pragma unroll
      for (int r = 0; r < 4; ++r) {
        int row = m0 + wm * 32 + mt * 16 + quad * 4 + r;
        if (row >= N_TOK) continue;
        int col = n_in + wn * 32 + nt * 16 + li;   // 0..319
        int h = col / DH, d = col % DH;
        float v = acc[mt][nt][r];
        if (wsel == 2) {
          vt[h * (48 * N_TOK) + d * N_TOK + row] = (bf16)v;   // transposed V
        } else {
          bf16* dst = wsel == 0 ? q : k;
          dst[h * (N_TOK * DH) + row * DH + d] = (bf16)v;
        }
      }
}

// ---------- flash attention: 16 q-rows/wave, 4 waves/block, online softmax ----------
__global__ __launch_bounds__(256) void attn_kernel(
    const bf16* __restrict__ q, const bf16* __restrict__ k, const bf16* __restrict__ vt,
    const unsigned int* __restrict__ mask32, bf16* __restrict__ attn) {
  __shared__ unsigned short pbuf[4][16][68];   // per-wave P tile, +4 shorts pad
  int bid = blockIdx.x;
  int h = bid & 7;                 // head fastest -> head h pins to one XCD's L2
  int qbase = (bid >> 3) * 64;
  int wv = threadIdx.x >> 6, lane = threadIdx.x & 63;
  int quad = lane >> 4, li = lane & 15;
  const bf16* qh = q + h * (N_TOK * DH);
  const bf16* kh = k + h * (N_TOK * DH);
  const bf16* vth = vt + h * (48 * N_TOK);

  int qrow_base = qbase + wv * 16;
  int qr = qrow_base + li; if (qr > N_TOK - 1) qr = N_TOK - 1;
  short8 qa0 = *(const short8*)(qh + qr * DH + quad * 8);
  short8 qa1 = (quad == 0) ? *(const short8*)(qh + qr * DH + 32) : (short8)0;

  unsigned int wq[4]; int qi[4];
#pragma unroll
  for (int r = 0; r < 4; ++r) {
    qi[r] = qrow_base + quad * 4 + r;
    wq[r] = mask32[qi[r]];
  }

  f32x4 o[3];
#pragma unroll
  for (int d = 0; d < 3; ++d) o[d] = (f32x4){0.f, 0.f, 0.f, 0.f};
  float mr[4], lr[4];
#pragma unroll
  for (int r = 0; r < 4; ++r) { mr[r] = -30000.f; lr[r] = 0.f; }

  const float c = 0.15811388300841898f * 1.4426950408889634f;  // scale * log2(e)

  for (int kt = 0; kt < 65; ++kt) {
    int j0 = kt * 64;
    f32x4 s[4];
    unsigned int wk[4]; int kj[4];
#pragma unroll
    for (int nt = 0; nt < 4; ++nt) {
      kj[nt] = j0 + nt * 16 + li;
      wk[nt] = mask32[kj[nt]];
      int krow = kj[nt] > N_TOK - 1 ? N_TOK - 1 : kj[nt];
      short8 kb0 = *(const short8*)(kh + krow * DH + quad * 8);
      s[nt] = __builtin_amdgcn_mfma_f32_16x16x32_bf16(qa0, kb0, (f32x4){0.f, 0.f, 0.f, 0.f}, 0, 0, 0);
      short8 kb1 = (quad == 0) ? *(const short8*)(kh + krow * DH + 32) : (short8)0;
      s[nt] = __builtin_amdgcn_mfma_f32_16x16x32_bf16(qa1, kb1, s[nt], 0, 0, 0);
    }
    // mask + scale (exp2 domain). Clamp keeps every exp2 arg in [-60000, 0];
    // IEEE min/max also scrub any non-finite logit to a masked-like value.
    float t[4][4];
#pragma unroll
    for (int nt = 0; nt < 4; ++nt)
#pragma unroll
      for (int r = 0; r < 4; ++r) {
        unsigned int mm = ((wq[r] & wk[nt]) & 0x1ffu) | ((wq[r] | wk[nt]) & 0x8000u);
        bool kp = (mm != 0u) || (qi[r] == kj[nt]);
        float tv = fminf(fmaxf(s[nt][r] * c, -20000.f), 20000.f);
        t[nt][r] = kp ? tv : -40000.f;
      }
    // row max over 64 cols (4 ntiles in-lane + 16-lane butterfly within quad)
    float mt_[4];
#pragma unroll
    for (int r = 0; r < 4; ++r) {
      float v = fmaxf(fmaxf(t[0][r], t[1][r]), fmaxf(t[2][r], t[3][r]));
      v = fmaxf(v, __shfl_xor(v, 1, 64));
      v = fmaxf(v, __shfl_xor(v, 2, 64));
      v = fmaxf(v, __shfl_xor(v, 4, 64));
      v = fmaxf(v, __shfl_xor(v, 8, 64));
      mt_[r] = v;
    }
    float alpha[4];
#pragma unroll
    for (int r = 0; r < 4; ++r) {
      float mn = fmaxf(mr[r], mt_[r]);
      alpha[r] = exp2f(mr[r] - mn);   // arg in [-50000, 0]
      mr[r] = mn;
    }
    float rs[4] = {0.f, 0.f, 0.f, 0.f};
#pragma unroll
    for (int nt = 0; nt < 4; ++nt)
#pragma unroll
      for (int r = 0; r < 4; ++r) {
        float p = exp2f(t[nt][r] - mr[r]);   // arg in [-60000, 0] -> p in [0,1]
        rs[r] += p;
        bf16 pb = (bf16)p;
        pbuf[wv][quad * 4 + r][nt * 16 + li] = __builtin_bit_cast(unsigned short, pb);
      }
#pragma unroll
    for (int r = 0; r < 4; ++r) {
      float v = rs[r];
      v += __shfl_xor(v, 1, 64);
      v += __shfl_xor(v, 2, 64);
      v += __shfl_xor(v, 4, 64);
      v += __shfl_xor(v, 8, 64);
      lr[r] = lr[r] * alpha[r] + v;
    }
#pragma unroll
    for (int d = 0; d < 3; ++d)
#pragma unroll
      for (int r = 0; r < 4; ++r) o[d][r] *= alpha[r];
    __syncthreads();   // drain pbuf writes (block-wide barrier; uniform trip count)
    // PV: P (A-layout from LDS) x Vt (B frags direct from global)
#pragma unroll
    for (int ksv = 0; ksv < 2; ++ksv) {
      union { short8 v; ushort4 u[2]; } fp;
      fp.u[0] = *(const ushort4*)&pbuf[wv][li][ksv * 32 + quad * 8];
      fp.u[1] = *(const ushort4*)&pbuf[wv][li][ksv * 32 + quad * 8 + 4];
      int jj = j0 + ksv * 32 + quad * 8;
      if (jj > N_TOK - 8) jj = N_TOK - 8;   // clamp stays in-row; clamped cols have P=0
#pragma unroll
      for (int dt = 0; dt < 3; ++dt) {
        short8 vb = *(const short8*)(vth + (dt * 16 + li) * N_TOK + jj);
        o[dt] = __builtin_amdgcn_mfma_f32_16x16x32_bf16(fp.v, vb, o[dt], 0, 0, 0);
      }
    }
    __syncthreads();   // keep next iteration's pbuf writes off this iteration's reads
  }
  float rl[4];
#pragma unroll
  for (int r = 0; r < 4; ++r) rl[r] = 1.0f / fmaxf(lr[r], 1e-20f);
#pragma unroll
  for (int dt = 0; dt < 3; ++dt) {
    int d = dt * 16 + li;
    if (d >= DH) continue;
#pragma unroll
    for (int r = 0; r < 4; ++r) {
      int row = qrow_base + quad * 4 + r;
      if (row >= N_TOK) continue;
      attn[row * QD + h * DH + d] = (bf16)(o[dt][r] * rl[r]);
    }
  }
}

// ---------- output projection + bias (dtype-aware bias read + final store) ----------
__global__ __launch_bounds__(256) void gemm_out(
    const bf16* __restrict__ A, const bf16* __restrict__ Bt,
    const void* __restrict__ bias, void* __restrict__ out,
    const int* __restrict__ flag) {
  bool isbf = flag[0] != 0;
  int m0 = blockIdx.x * 64;
  int n0 = blockIdx.y * 64;
  int wv = threadIdx.x >> 6, lane = threadIdx.x & 63;
  int quad = lane >> 4, li = lane & 15;
  int wm = wv >> 1, wn = wv & 1;
  f32x4 acc[2][2];
#pragma unroll
  for (int a = 0; a < 2; a++)
#pragma unroll
    for (int b = 0; b < 2; b++) acc[a][b] = (f32x4){0.f, 0.f, 0.f, 0.f};
#pragma unroll
  for (int ks = 0; ks < 10; ++ks) {
    short8 af[2], bfrag[2];
#pragma unroll
    for (int mt = 0; mt < 2; ++mt) {
      int r = m0 + wm * 32 + mt * 16 + li;
      r = r < N_TOK ? r : N_TOK - 1;
      af[mt] = *(const short8*)(A + r * QD + ks * 32 + quad * 8);
    }
#pragma unroll
    for (int nt = 0; nt < 2; ++nt) {
      int r = n0 + wn * 32 + nt * 16 + li;
      bfrag[nt] = *(const short8*)(Bt + r * QD + ks * 32 + quad * 8);
    }
#pragma unroll
    for (int mt = 0; mt < 2; ++mt)
#pragma unroll
      for (int nt = 0; nt < 2; ++nt)
        acc[mt][nt] = __builtin_amdgcn_mfma_f32_16x16x32_bf16(af[mt], bfrag[nt], acc[mt][nt], 0, 0, 0);
  }
#pragma unroll
  for (int mt = 0; mt < 2; ++mt)
#pragma unroll
    for (int nt = 0; nt < 2; ++nt)
#pragma unroll
      for (int r = 0; r < 4; ++r) {
        int row = m0 + wm * 32 + mt * 16 + quad * 4 + r;
        if (row >= N_TOK) continue;
        int col = n0 + wn * 32 + nt * 16 + li;
        float val = acc[mt][nt][r] + loadS(bias, col, isbf);
        if (isbf) ((bf16*)out)[row * QD + col] = (bf16)val;
        else      ((float*)out)[row * QD + col] = val;
      }
}

extern "C" void kernel_launch(void* const* d_in, const int* in_sizes, int n_in,
                              void* d_out, int out_size, void* d_ws, size_t ws_size,
                              hipStream_t stream) {
  (void)in_sizes; (void)n_in; (void)out_size; (void)ws_size;
  const void* x   = d_in[0];
  const void* att = d_in[1];
  const void* Wq  = d_in[2];
  const void* Wk  = d_in[3];
  const void* Wv  = d_in[4];
  const void* Wo  = d_in[5];
  const void* bo  = d_in[6];
  char* ws = (char*)d_ws;
  // layout (bytes)
  bf16* Wqt = (bf16*)(ws + 0);
  bf16* Wkt = (bf16*)(ws + 204800);
  bf16* Wvt = (bf16*)(ws + 409600);
  bf16* Wot = (bf16*)(ws + 614400);
  unsigned int* mask32 = (unsigned int*)(ws + 819200);
  bf16* qb   = (bf16*)(ws + 835840);                       // 8*4128*40*2 = 2641920
  bf16* kb   = (bf16*)(ws + 835840 + 2641920);
  bf16* vt   = (bf16*)(ws + 835840 + 2 * 2641920);         // 8*48*4128*2 = 3170304
  bf16* attn = (bf16*)(ws + 835840 + 2 * 2641920 + 3170304);
  int* flag  = (int*)(ws + 835840 + 3 * 2641920 + 3170304);

  hipMemsetAsync(vt, 0, 3170304, stream);  // zero V-transpose pad rows (d=40..47)
  sniff_kernel<<<1, 256, 0, stream>>>((const unsigned short*)att, flag);
  prep_kernel<<<1617, 256, 0, stream>>>(att, Wq, Wk, Wv, Wo, Wqt, Wkt, Wvt, Wot, mask32, flag);
  dim3 g1(65, 15);
  gemm_qkv<<<g1, 256, 0, stream>>>(x, Wqt, Wkt, Wvt, qb, kb, vt, flag);
  attn_kernel<<<520, 256, 0, stream>>>(qb, kb, vt, mask32, attn);
  dim3 g2(65, 5);
  gemm_out<<<g2, 256, 0, stream>>>(attn, Wot, bo, d_out, flag);
}